// Round 7
// baseline (134.843 us; speedup 1.0000x reference)
//
#include <hip/hip_runtime.h>
#include <math.h>

// NGRU via MFMA, R7 = R5 shell + x-direct-to-registers + bias-in-acc.
// Only layer 1 of the 2 parallel GRU layers contributes (reference returns
// h_final[-1]); layer 0 is skipped.
//
// Shapes: x (64,48,256,64) f32; Wih/Whh (2,192,64); bih/bhh (2,192).
// rows = B*N = 16384 independent GRU sequences, T=48, H=64.
//
// Structure: 512 blocks x 256 threads (4 waves), 32 rows/block, 2 blocks/CU
// (R6 proved 16-row/4-domain blocks regress: per-barrier phases too short).
// Wave nw owns output columns j in [16nw,16nw+16) for ALL FOUR gates
// (g=0:r, 1:z, 2:gin, 3:ghn) -> gate epilogue fully register-local.
//
// R7 changes vs R5:
//  * x is NOT recurrent -> each thread loads its own x MFMA-fragments
//    (32 floats) straight from global into REGISTERS during step t-1 and
//    converts to bf16 hi/lo privately. x vanishes from LDS entirely:
//    -8 ds_read_b128, -2 ds_write_b128 per thread/step, and the 36 x-part
//    MFMAs issue right after the barrier with zero LDS latency, hiding the
//    h-part ds_read latency. L2 absorbs the 4x intra-block re-read.
//  * Gate biases preloaded into the MFMA accumulators (bias is constant
//    across the 4 C-regs of a tile): -32 epilogue adds.
//  * LDS: h-only bf16 hi/lo planes [32][HK=72], ping-ponged, lo-plane
//    staggered +16 shorts == +8 banks -> paired h dword writes (even lane
//    hi-plane, odd lane lo-plane) hit all 32 banks 2-way = free.
//
// Split-bf16: v = hi + lo; product = AhBh + AhBl + AlBh (~2^-17 rel).

#define TT 48
#define HH 64
#define GG 192
#define NN 256
#define RPB 32          // rows per block
#define NTHREADS 256    // 4 waves
#define HK 72           // h row stride in shorts (64 + 8 pad)
#define PLANE (RPB*HK + 16)  // 2320 shorts; +16 = +8 banks lo-plane stagger
#define ABUF (2*PLANE)

typedef __attribute__((ext_vector_type(8))) short bs8;       // 8 bf16
typedef __attribute__((ext_vector_type(4))) float f32x4;     // MFMA accum
typedef __attribute__((ext_vector_type(4))) unsigned u32x4;

__device__ __forceinline__ float sigm(float v) {
    return __builtin_amdgcn_rcpf(1.f + __expf(-v));
}
__device__ __forceinline__ float tanh_f(float v) {
    float a = fabsf(v);
    float e = __expf(2.f * a);
    float t = 1.f - 2.f * __builtin_amdgcn_rcpf(e + 1.f);
    return v < 0.f ? -t : t;
}
// packed f32x2 -> bf16x2 (RNE): D[15:0]=bf16(S0), D[31:16]=bf16(S1)
__device__ __forceinline__ unsigned cvtpk(float lo, float hi) {
    unsigned r;
    asm("v_cvt_pk_bf16_f32 %0, %1, %2" : "=v"(r) : "v"(lo), "v"(hi));
    return r;
}
__device__ __forceinline__ float ubits(unsigned u) { return __uint_as_float(u); }
// scalar RNE helpers (B build only; one-time)
__device__ __forceinline__ unsigned short f2bf(float f) {
    unsigned u = __float_as_uint(f);
    return (unsigned short)((u + 0x7fffu + ((u >> 16) & 1u)) >> 16);
}
__device__ __forceinline__ float bf2f(unsigned short b) {
    return __uint_as_float(((unsigned)b) << 16);
}
// 8 consecutive f32 -> bf16 hi/lo fragments
__device__ __forceinline__ void cvt8(float4 a, float4 b, bs8& h8, bs8& l8) {
    unsigned h0 = cvtpk(a.x, a.y), h1 = cvtpk(a.z, a.w);
    unsigned h2 = cvtpk(b.x, b.y), h3 = cvtpk(b.z, b.w);
    unsigned l0 = cvtpk(a.x - ubits(h0 << 16), a.y - ubits(h0 & 0xffff0000u));
    unsigned l1 = cvtpk(a.z - ubits(h1 << 16), a.w - ubits(h1 & 0xffff0000u));
    unsigned l2 = cvtpk(b.x - ubits(h2 << 16), b.y - ubits(h2 & 0xffff0000u));
    unsigned l3 = cvtpk(b.z - ubits(h3 << 16), b.w - ubits(h3 & 0xffff0000u));
    h8 = __builtin_bit_cast(bs8, (u32x4){h0, h1, h2, h3});
    l8 = __builtin_bit_cast(bs8, (u32x4){l0, l1, l2, l3});
}

#define MFMA3(ACC, AH, AL, S)                                                   \
    ACC = __builtin_amdgcn_mfma_f32_16x16x32_bf16(AH, Bh[S], ACC, 0, 0, 0);     \
    ACC = __builtin_amdgcn_mfma_f32_16x16x32_bf16(AH, Bl[S], ACC, 0, 0, 0);     \
    ACC = __builtin_amdgcn_mfma_f32_16x16x32_bf16(AL, Bh[S], ACC, 0, 0, 0);

__global__ __launch_bounds__(NTHREADS, 2)
void ngru_mfma7(const float* __restrict__ x,
                const float* __restrict__ Wih,
                const float* __restrict__ Whh,
                const float* __restrict__ bih,
                const float* __restrict__ bhh,
                float* __restrict__ out)
{
    extern __shared__ __align__(16) short lds_s[];   // 2 x ABUF shorts (h only)

    const int tid  = threadIdx.x;
    const int lane = tid & 63;
    const int nw   = tid >> 6;          // wave 0..3 -> j slice [16nw,16nw+16)
    const int c0   = lane & 15;         // C col within tile / A row index
    const int rq   = lane >> 4;         // quarter-wave
    const int j    = nw * 16 + c0;
    const bool odd = (c0 & 1);

    const int grow0 = blockIdx.x * RPB;
    const int bb    = grow0 / NN;
    const int n0    = grow0 % NN;

    const float* Wi = Wih + GG * HH;    // layer 1
    const float* Wh = Whh + GG * HH;

    // ---- B fragments in registers: 12 kt-slots (zero tiles skipped) ----
    bs8 Bh[12], Bl[12];
    #pragma unroll
    for (int g = 0; g < 4; ++g) {
        const int ktlo = (g == 3) ? 2 : 0;
        const int kthi = (g == 2) ? 2 : 4;
        #pragma unroll
        for (int kt = ktlo; kt < kthi; ++kt) {
            const int slot = (g < 2) ? g * 4 + kt : 8 + (g - 2) * 2 + (kt & 1);
            const bool isWi = (kt < 2);
            const int gbase = (g >= 2) ? 2 : g;
            const float* src = (isWi ? Wi : Wh)
                             + (gbase * 64 + j) * HH + (kt & 1) * 32 + rq * 8;
            bs8 h8, l8;
            #pragma unroll
            for (int q = 0; q < 8; ++q) {
                float v = src[q];
                unsigned short hb = f2bf(v);
                unsigned short lb = f2bf(v - bf2f(hb));
                h8[q] = (short)hb; l8[q] = (short)lb;
            }
            Bh[slot] = h8; Bl[slot] = l8;
        }
    }

    // ---- biases (layer 1), r/z pre-summed; n biases stay separate ----
    const float brz  = bih[GG + j]      + bhh[GG + j];
    const float bzz  = bih[GG + 64 + j] + bhh[GG + 64 + j];
    const float bi_n = bih[GG + 128 + j];
    const float bh_n = bhh[GG + 128 + j];

    // ---- init: zero h region of buf0 (both planes) ----
    {
        const int zr = tid >> 3;          // 0..31
        const int zc = (tid & 7) * 8;     // 0..56
        bs8 z = {0,0,0,0,0,0,0,0};
        *(bs8*)(lds_s + zr * HK + zc)         = z;
        *(bs8*)(lds_s + PLANE + zr * HK + zc) = z;
    }

    // ---- x fragment registers for the CURRENT step (load t=0 now) ----
    // frag (m,kt): A rows m*16+c0, k = kt*32 + rq*8 .. +8
    bs8 Xh[2][2], Xl[2][2];
    {
        const float* xb = x + ((size_t)(bb * TT) * NN + n0) * HH;
        #pragma unroll
        for (int m = 0; m < 2; ++m)
            #pragma unroll
            for (int kt = 0; kt < 2; ++kt) {
                const float* src = xb + (m * 16 + c0) * HH + kt * 32 + rq * 8;
                float4 a = *(const float4*)src;
                float4 b = *(const float4*)(src + 4);
                cvt8(a, b, Xh[m][kt], Xl[m][kt]);
            }
    }

    float hreg[2][4];
    #pragma unroll
    for (int m = 0; m < 2; ++m)
        #pragma unroll
        for (int r = 0; r < 4; ++r) hreg[m][r] = 0.f;

    __syncthreads();   // buf0 h-region ready for t=0

    for (int t = 0; t < TT; ++t) {
        short* cur = lds_s + (t & 1) * ABUF;
        short* nxt = lds_s + ((t & 1) ^ 1) * ABUF;
        const bool hasNext = (t + 1 < TT);

        // acc preloaded with biases (constant across the 4 C-regs of a tile)
        f32x4 acc[2][4];
        #pragma unroll
        for (int m = 0; m < 2; ++m) {
            acc[m][0] = (f32x4){brz,  brz,  brz,  brz };
            acc[m][1] = (f32x4){bzz,  bzz,  bzz,  bzz };
            acc[m][2] = (f32x4){bi_n, bi_n, bi_n, bi_n};
            acc[m][3] = (f32x4){bh_n, bh_n, bh_n, bh_n};
        }

        // issue h-part A reads first (latency overlaps x-part MFMAs)
        bs8 Hh[2][2], Hl[2][2];
        #pragma unroll
        for (int m = 0; m < 2; ++m)
            #pragma unroll
            for (int kt = 0; kt < 2; ++kt) {
                const short* ab = cur + (m * 16 + c0) * HK + kt * 32 + rq * 8;
                Hh[m][kt] = *(const bs8*)ab;
                Hl[m][kt] = *(const bs8*)(ab + PLANE);
            }

        __builtin_amdgcn_s_setprio(1);
        // x-part MFMAs from registers: gates r, z, gin (zero LDS latency)
        #pragma unroll
        for (int m = 0; m < 2; ++m)
            #pragma unroll
            for (int kt = 0; kt < 2; ++kt) {
                MFMA3(acc[m][0], Xh[m][kt], Xl[m][kt], kt);       // r
                MFMA3(acc[m][1], Xh[m][kt], Xl[m][kt], 4 + kt);   // z
                MFMA3(acc[m][2], Xh[m][kt], Xl[m][kt], 8 + kt);   // gin
            }
        // h-part MFMAs: gates r, z, ghn
        #pragma unroll
        for (int m = 0; m < 2; ++m)
            #pragma unroll
            for (int kt = 0; kt < 2; ++kt) {
                MFMA3(acc[m][0], Hh[m][kt], Hl[m][kt], 2 + kt);   // r
                MFMA3(acc[m][1], Hh[m][kt], Hl[m][kt], 6 + kt);   // z
                MFMA3(acc[m][3], Hh[m][kt], Hl[m][kt], 10 + kt);  // ghn
            }
        __builtin_amdgcn_s_setprio(0);

        // prefetch x(t+1) into registers (latency hides under epilogue)
        float4 pa[2][2], pb[2][2];
        if (hasNext) {
            const float* xb = x + ((size_t)(bb * TT + t + 1) * NN + n0) * HH;
            #pragma unroll
            for (int m = 0; m < 2; ++m)
                #pragma unroll
                for (int kt = 0; kt < 2; ++kt) {
                    const float* src = xb + (m * 16 + c0) * HH + kt * 32 + rq * 8;
                    pa[m][kt] = *(const float4*)src;
                    pb[m][kt] = *(const float4*)(src + 4);
                }
        }

        // ===== epilogue: register-local gates; h -> nxt buffer =====
        short* hp = nxt + (odd ? PLANE : 0);
        #pragma unroll
        for (int m = 0; m < 2; ++m) {
            #pragma unroll
            for (int r = 0; r < 4; ++r) {
                const int row = m * 16 + rq * 4 + r;
                float rg = sigm(acc[m][0][r]);
                float zg = sigm(acc[m][1][r]);
                float ng = tanh_f(fmaf(rg, acc[m][3][r], acc[m][2][r]));
                float hn = fmaf(zg, hreg[m][r] - ng, ng);   // (1-z)n + z h
                hreg[m][r] = hn;
                if (hasNext) {
                    // paired dword write: even lane -> hi-plane dword {j,j+1},
                    // odd lane -> lo-plane dword; planes staggered 8 banks
                    // -> combined 64-lane write covers 32 banks 2-way (free)
                    float partner = __shfl_xor(hn, 1);
                    float ve = odd ? partner : hn;     // value at even column
                    float vo = odd ? hn : partner;     // value at odd column
                    unsigned hd = cvtpk(ve, vo);
                    float re = ve - ubits(hd << 16);
                    float ro = vo - ubits(hd & 0xffff0000u);
                    unsigned ld = cvtpk(re, ro);
                    unsigned w = odd ? ld : hd;
                    *(unsigned*)(hp + row * HK + (j & ~1)) = w;
                }
            }
        }

        if (hasNext) {
            // convert x(t+1) into fragment registers (global latency elapsed)
            #pragma unroll
            for (int m = 0; m < 2; ++m)
                #pragma unroll
                for (int kt = 0; kt < 2; ++kt)
                    cvt8(pa[m][kt], pb[m][kt], Xh[m][kt], Xl[m][kt]);
            __syncthreads();   // nxt h ready for step t+1
        }
    }

    #pragma unroll
    for (int m = 0; m < 2; ++m)
        #pragma unroll
        for (int r = 0; r < 4; ++r)
            out[(size_t)(grow0 + m * 16 + rq * 4 + r) * HH + j] = hreg[m][r];
}

extern "C" void kernel_launch(void* const* d_in, const int* in_sizes, int n_in,
                              void* d_out, int out_size, void* d_ws, size_t ws_size,
                              hipStream_t stream) {
    const float* x   = (const float*)d_in[0];
    const float* Wih = (const float*)d_in[1];
    const float* Whh = (const float*)d_in[2];
    const float* bih = (const float*)d_in[3];
    const float* bhh = (const float*)d_in[4];
    float* out = (float*)d_out;

    const int lds_bytes = 2 * ABUF * (int)sizeof(short);   // 18,560 B
    (void)hipFuncSetAttribute((const void*)ngru_mfma7,
                        hipFuncAttributeMaxDynamicSharedMemorySize, lds_bytes);

    dim3 grid(16384 / RPB);     // 512 blocks, 2 per CU
    dim3 block(NTHREADS);
    ngru_mfma7<<<grid, block, lds_bytes, stream>>>(x, Wih, Whh, bih, bhh, out);
}